// Round 5
// baseline (404.608 us; speedup 1.0000x reference)
//
#include <hip/hip_runtime.h>
#include <cstdint>
#include <cstddef>

#define TOPK 700
#define NPIX 4096   // 64*64
#define NG 4
#define NE 8
#define NW 36       // (E+1)*G

typedef float nt_float4 __attribute__((ext_vector_type(4)));  // native vec for nt store

// ---------------------------------------------------------------------------
// Kernel A: sigmoid + exact top-700 (jax.lax.top_k order: value desc, index asc)
// Rank-by-counting on sortable u64 keys: (float_bits(sigmoid) << 12) | (4095-i).
// 64 blocks/batch, 256 thr; 4 threads per element each scan 1/4 of the keys.
// ---------------------------------------------------------------------------
__global__ __launch_bounds__(256) void topk_kernel(
    const float* __restrict__ logits,
    int* __restrict__ sel_idx,
    float* __restrict__ scores_out) {
  __shared__ __attribute__((aligned(16))) unsigned long long keys[NPIX];

  const int b   = blockIdx.x >> 6;   // 64 blocks per batch
  const int blk = blockIdx.x & 63;
  const float* src = logits + b * NPIX;

  for (int i = threadIdx.x; i < NPIX; i += 256) {
    float x = src[i];
    float s = 1.0f / (1.0f + expf(-x));           // precise expf for stable ordering
    keys[i] = (((unsigned long long)__float_as_uint(s)) << 12)
              | (unsigned long long)(4095 - i);    // tie-break: lower index = larger key
  }
  __syncthreads();

  const int e = blk * 64 + (threadIdx.x >> 2);     // element this group of 4 owns
  const int q = threadIdx.x & 3;                   // quarter of the scan
  const unsigned long long mykey = keys[e];

  const ulonglong2* k2 = (const ulonglong2*)keys;  // 2048 pairs
  int rank = 0;
  const int base = q * 512;
  #pragma unroll 8
  for (int jj = 0; jj < 512; ++jj) {
    ulonglong2 kk = k2[base + jj];
    rank += (kk.x > mykey);
    rank += (kk.y > mykey);
  }
  rank += __shfl_xor(rank, 1);
  rank += __shfl_xor(rank, 2);

  if (q == 0 && rank < TOPK) {
    int idx = 4095 - (int)(mykey & 0xFFFULL);
    sel_idx[b * TOPK + rank]    = idx;
    scores_out[b * TOPK + rank] = __uint_as_float((unsigned)(mykey >> 12));
  }
}

// ---------------------------------------------------------------------------
// R5 split, kernel B1: per (b,k) compute the full 64x64 sigmoid-product tile
// (identical fmaf/exp chain to the verified kernel) and write it to a 23 MB
// workspace buffer with REGULAR stores (L2-allocating; B2 reads it back).
// ---------------------------------------------------------------------------
__global__ __launch_bounds__(256) void tile_kernel(
    const float* __restrict__ enc,       // [B, 8, 4096]
    const float* __restrict__ weights,   // [B, 36, 4096]
    const int* __restrict__ sel_idx,     // [B*700]
    float* __restrict__ tiles) {         // [B*700, 4096]
  __shared__ float ws[NW];

  const int bk  = blockIdx.x;            // 0..1399
  const int b   = (bk >= TOPK) ? 1 : 0;
  const int tid = threadIdx.x;

  const int p = sel_idx[bk];             // selected pixel (h*64+w), uniform
  if (tid < NW) ws[tid] = weights[(size_t)(b * NW + tid) * NPIX + p];
  __syncthreads();

  float wreg[NW];
  #pragma unroll
  for (int c = 0; c < NW; ++c) wreg[c] = ws[c];   // LDS broadcast, once

  const float* eb = enc + (size_t)b * NE * NPIX;
  float* tb = tiles + (size_t)bk * NPIX;

  #pragma unroll
  for (int it = 0; it < 4; ++it) {
    int p4 = (tid + 256 * it) * 4;       // 4 consecutive pixels
    float4 ev[NE];
    #pragma unroll
    for (int ch = 0; ch < NE; ++ch)
      ev[ch] = *(const float4*)(eb + (size_t)ch * NPIX + p4);
    float4 s = make_float4(1.f, 1.f, 1.f, 1.f);
    #pragma unroll
    for (int g = 0; g < NG; ++g) {
      float zx = wreg[g * 9 + 8], zy = zx, zz = zx, zw = zx;  // bias
      #pragma unroll
      for (int ch = 0; ch < NE; ++ch) {
        float w = wreg[g * 9 + ch];
        zx = fmaf(w, ev[ch].x, zx);
        zy = fmaf(w, ev[ch].y, zy);
        zz = fmaf(w, ev[ch].z, zz);
        zw = fmaf(w, ev[ch].w, zw);
      }
      s.x *= __builtin_amdgcn_rcpf(1.f + __expf(-zx));
      s.y *= __builtin_amdgcn_rcpf(1.f + __expf(-zy));
      s.z *= __builtin_amdgcn_rcpf(1.f + __expf(-zz));
      s.w *= __builtin_amdgcn_rcpf(1.f + __expf(-zw));
    }
    *(float4*)(tb + p4) = s;
  }
}

// ---------------------------------------------------------------------------
// R5 split, kernel B2: pure streaming upsample. Grid-stride over all
// 1400*256 output rows; one wave per row: 2 coalesced 256B loads (rows y0,y1
// from the L2-resident tile), neighbors via in-wave __shfl, 12 FMA, 1 nt
// store of float4. ~25 VGPR, no LDS, no barriers -> max store concurrency.
// Expression-identical arithmetic to the verified fused kernel.
// ---------------------------------------------------------------------------
__global__ __launch_bounds__(256) void upsample_kernel(
    const float* __restrict__ tiles,     // [B*700, 4096]
    float* __restrict__ out_m) {         // [B*700, 256, 256]
  const int lane = threadIdx.x & 63;
  const int wv   = threadIdx.x >> 6;
  const int lm   = (lane > 0)  ? lane - 1 : 0;
  const int lp   = (lane < 63) ? lane + 1 : 63;

  const int nrows = 2 * TOPK * 256;      // 358400
  for (int r = blockIdx.x * 4 + wv; r < nrows; r += gridDim.x * 4) {
    const int bk = r >> 8;
    const int oy = r & 255;

    const float in_y = oy * 0.25f - 0.375f;   // (oy+0.5)/4 - 0.5, exact
    const float fy0  = floorf(in_y);
    const float wy   = in_y - fy0;            // 0.125/0.375/0.625/0.875 exact
    const int y0  = (int)fy0;
    const int y0c = (y0 > 0) ? y0 : 0;
    const int y1c = (y0 + 1 < 63) ? y0 + 1 : 63;

    const float* t0 = tiles + (size_t)bk * NPIX + y0c * 64;
    const float* t1 = tiles + (size_t)bk * NPIX + y1c * 64;
    float a0 = t0[lane];
    float b0 = t1[lane];
    float am = __shfl(a0, lm, 64), ap = __shfl(a0, lp, 64);
    float bm = __shfl(b0, lm, 64), bp = __shfl(b0, lp, 64);

    float vm = fmaf(wy, bm - am, am);
    float v0 = fmaf(wy, b0 - a0, a0);
    float vp = fmaf(wy, bp - ap, ap);
    nt_float4 o;
    o.x = vm * 0.375f + v0 * 0.625f;   // ox=4*lane+0: frac 0.625 from col lane-1
    o.y = vm * 0.125f + v0 * 0.875f;   // ox=4*lane+1
    o.z = v0 * 0.875f + vp * 0.125f;   // ox=4*lane+2
    o.w = v0 * 0.625f + vp * 0.375f;   // ox=4*lane+3
    __builtin_nontemporal_store(
        o, (nt_float4*)(out_m + (size_t)bk * 65536 + (size_t)oy * 256 + 4 * lane));
  }
}

// ---------------------------------------------------------------------------
// Fallback (verified R4 fused kernel) — used only if ws_size can't hold the
// tile buffer. 4 blocks per (b,k), 18-row halo'd LDS strip, nt stores.
// ---------------------------------------------------------------------------
__global__ __launch_bounds__(256) void mask_kernel(
    const float* __restrict__ enc,       // [B, 8, 4096]
    const float* __restrict__ weights,   // [B, 36, 4096]
    const int* __restrict__ sel_idx,     // [B*700]
    float* __restrict__ out_m) {         // [B*700, 256, 256]
  __shared__ float ws[NW];
  __shared__ __attribute__((aligned(16))) float tile[18 * 64];  // 4.5 KB

  const int blk = blockIdx.x;            // 0..5599
  const int bk  = blk >> 2;              // 0..1399
  const int qs  = blk & 3;               // strip index: out rows [64qs, 64qs+63]
  const int b   = (bk >= TOPK) ? 1 : 0;
  const int tid = threadIdx.x;

  const int p = sel_idx[bk];             // selected pixel (h*64+w), uniform
  if (tid < NW) ws[tid] = weights[(size_t)(b * NW + tid) * NPIX + p];
  __syncthreads();

  float wreg[NW];
  #pragma unroll
  for (int c = 0; c < NW; ++c) wreg[c] = ws[c];   // LDS broadcast, once

  const int row0 = qs * 16 - 1;
  const float* eb = enc + (size_t)b * NE * NPIX;

  #pragma unroll
  for (int pass = 0; pass < 2; ++pass) {
    if (pass == 0 || tid < 32) {
      const int qq   = tid + pass * 256;
      const int j    = qq >> 4;
      const int col4 = (qq & 15) << 2;
      const int g    = row0 + j;
      const int gc   = (g < 0) ? 0 : ((g > 63) ? 63 : g);
      const int src4 = gc * 64 + col4;
      float4 ev[NE];
      #pragma unroll
      for (int ch = 0; ch < NE; ++ch)
        ev[ch] = *(const float4*)(eb + (size_t)ch * NPIX + src4);
      float4 s = make_float4(1.f, 1.f, 1.f, 1.f);
      #pragma unroll
      for (int g2 = 0; g2 < NG; ++g2) {
        float zx = wreg[g2 * 9 + 8], zy = zx, zz = zx, zw = zx;  // bias
        #pragma unroll
        for (int ch = 0; ch < NE; ++ch) {
          float w = wreg[g2 * 9 + ch];
          zx = fmaf(w, ev[ch].x, zx);
          zy = fmaf(w, ev[ch].y, zy);
          zz = fmaf(w, ev[ch].z, zz);
          zw = fmaf(w, ev[ch].w, zw);
        }
        s.x *= __builtin_amdgcn_rcpf(1.f + __expf(-zx));
        s.y *= __builtin_amdgcn_rcpf(1.f + __expf(-zy));
        s.z *= __builtin_amdgcn_rcpf(1.f + __expf(-zz));
        s.w *= __builtin_amdgcn_rcpf(1.f + __expf(-zw));
      }
      *(float4*)(&tile[j * 64 + col4]) = s;
    }
  }
  __syncthreads();

  const int tx = tid & 63;
  const int ty = tid >> 6;

  const int cxm = (tx > 0) ? tx - 1 : 0;
  const int cxp = (tx < 63) ? tx + 1 : 63;

  const float base_y = ty * 0.25f - 0.375f;
  const float fy0 = floorf(base_y);
  const float wy  = base_y - fy0;
  const int jbase = (ty < 2) ? 0 : 1;

  float* orow = out_m + (size_t)bk * 65536 + (size_t)(qs * 64 + ty) * 256 + 4 * tx;

  const float* r0 = &tile[jbase * 64];
  float am = r0[cxm], a0 = r0[tx], ap = r0[cxp];

  #pragma unroll 4
  for (int i = 0; i < 16; ++i) {
    const float* r1 = &tile[(jbase + i + 1) * 64];
    float bm = r1[cxm], b0 = r1[tx], bp = r1[cxp];
    float vm = fmaf(wy, bm - am, am);
    float v0 = fmaf(wy, b0 - a0, a0);
    float vp = fmaf(wy, bp - ap, ap);
    nt_float4 o;
    o.x = vm * 0.375f + v0 * 0.625f;
    o.y = vm * 0.125f + v0 * 0.875f;
    o.z = v0 * 0.875f + vp * 0.125f;
    o.w = v0 * 0.625f + vp * 0.375f;
    __builtin_nontemporal_store(o, (nt_float4*)(orow + (size_t)i * 1024));
    am = bm; a0 = b0; ap = bp;
  }
}

extern "C" void kernel_launch(void* const* d_in, const int* in_sizes, int n_in,
                              void* d_out, int out_size, void* d_ws, size_t ws_size,
                              hipStream_t stream) {
  const float* logits  = (const float*)d_in[0];  // (2,1,64,64)
  const float* enc     = (const float*)d_in[1];  // (2,8,64,64)
  const float* weights = (const float*)d_in[2];  // (2,36,64,64)

  float* out        = (float*)d_out;
  float* out_m      = out;                                    // 2*700*256*256
  float* out_scores = out + (size_t)2 * TOPK * 256 * 256;     // 2*700
  int*   sel_idx    = (int*)d_ws;                             // 2*700 ints

  topk_kernel<<<128, 256, 0, stream>>>(logits, sel_idx, out_scores);

  const size_t tiles_off  = 8192;  // keep sel_idx region, 16B-aligned
  const size_t tiles_need = tiles_off + (size_t)2 * TOPK * NPIX * sizeof(float);
  if (ws_size >= tiles_need) {
    float* tiles = (float*)((char*)d_ws + tiles_off);
    tile_kernel<<<2 * TOPK, 256, 0, stream>>>(enc, weights, sel_idx, tiles);
    upsample_kernel<<<2048, 256, 0, stream>>>(tiles, out_m);
  } else {
    mask_kernel<<<4 * 2 * TOPK, 256, 0, stream>>>(enc, weights, sel_idx, out_m);
  }
}